// Round 7
// baseline (187.357 us; speedup 1.0000x reference)
//
#include <hip/hip_runtime.h>

#define OC 32
#define IC 16
#define HH 128
#define WW 128
#define NB 8
#define NG 4              // channel groups (threadIdx.y)
#define CPG (OC / NG)     // 8 channels per group
#define NM (IC * 3)       // 48 (j,k) pairs

// Thread = (w-lane, channel group), computes 2 h-pixels x 8 channels.
// Block: threadIdx.x in [0,64) -> w within 64-chunk, threadIdx.y -> group.
// Grid: bid = n*128 + hpair*2 + wchunk   (8*64*2 = 1024 blocks)
__global__ __launch_bounds__(256, 4) void qconv_kernel(
        const float* __restrict__ x,
        const float* __restrict__ theta,
        float* __restrict__ out) {
    __shared__ float cw_s[NM * OC];
    __shared__ float sw_s[NM * OC];

    int t = threadIdx.y * 64 + threadIdx.x;
#pragma unroll
    for (int q = t; q < NM * OC; q += 256) {
        int m = q >> 5;
        int i = q & 31;
        int j = m / 3;
        int k = m - j * 3;
        float v = theta[(i * j) * 3 + k];
        float sn, cs;
        __sincosf(v, &sn, &cs);
        cw_s[q] = cs;
        sw_s[q] = -sn;
    }
    __syncthreads();

    int bid = blockIdx.x;
    int wbase = (bid & 1) * 64;
    int hp = (bid >> 1) & 63;
    int n = bid >> 7;
    int h0 = hp * 2;
    int w = wbase + threadIdx.x;
    int g = threadIdx.y;

    float acc0[CPG], acc1[CPG];
#pragma unroll
    for (int c = 0; c < CPG; ++c) { acc0[c] = 0.f; acc1[c] = 0.f; }

    const float* xn = x + (size_t)n * IC * HH * WW;
    const float* cwg = cw_s + g * CPG;
    const float* swg = sw_s + g * CPG;

    bool wl = (w > 0), wr = (w < WW - 1);

#pragma unroll 4
    for (int j = 0; j < IC; ++j) {
        const float* xj = xn + j * HH * WW;
        // window sums for rows h0-1 .. h0+2
        float rs[4];
#pragma unroll
        for (int tt = 0; tt < 4; ++tt) {
            int r = h0 - 1 + tt;
            float s = 0.f;
            if (r >= 0 && r < HH) {
                const float* row = xj + r * WW;
                float c0 = row[w];
                float cm = wl ? row[w - 1] : 0.f;
                float cp = wr ? row[w + 1] : 0.f;
                s = cm + c0 + cp;
            }
            rs[tt] = s;
        }
        float sn[4], cs[4];
#pragma unroll
        for (int tt = 0; tt < 4; ++tt) __sincosf(rs[tt], &sn[tt], &cs[tt]);

#pragma unroll
        for (int k = 0; k < 3; ++k) {
            int m = j * 3 + k;
            const float4* c4 = (const float4*)(cwg + m * OC);
            const float4* s4 = (const float4*)(swg + m * OC);
            float cs0 = cs[k], sn0 = sn[k];
            float cs1 = cs[k + 1], sn1 = sn[k + 1];
#pragma unroll
            for (int q = 0; q < 2; ++q) {
                float4 cc = c4[q];
                float4 ss = s4[q];
                acc0[4*q+0] = fmaf(cs0, cc.x, fmaf(sn0, ss.x, acc0[4*q+0]));
                acc0[4*q+1] = fmaf(cs0, cc.y, fmaf(sn0, ss.y, acc0[4*q+1]));
                acc0[4*q+2] = fmaf(cs0, cc.z, fmaf(sn0, ss.z, acc0[4*q+2]));
                acc0[4*q+3] = fmaf(cs0, cc.w, fmaf(sn0, ss.w, acc0[4*q+3]));
                acc1[4*q+0] = fmaf(cs1, cc.x, fmaf(sn1, ss.x, acc1[4*q+0]));
                acc1[4*q+1] = fmaf(cs1, cc.y, fmaf(sn1, ss.y, acc1[4*q+1]));
                acc1[4*q+2] = fmaf(cs1, cc.z, fmaf(sn1, ss.z, acc1[4*q+2]));
                acc1[4*q+3] = fmaf(cs1, cc.w, fmaf(sn1, ss.w, acc1[4*q+3]));
            }
        }
    }

    const float inv3 = 1.0f / 3.0f;
    float* outp = out + ((size_t)n * OC + g * CPG) * HH * WW + (size_t)h0 * WW + w;
#pragma unroll
    for (int c = 0; c < CPG; ++c) {
        outp[(size_t)c * HH * WW]      = acc0[c] * inv3;
        outp[(size_t)c * HH * WW + WW] = acc1[c] * inv3;
    }
}

extern "C" void kernel_launch(void* const* d_in, const int* in_sizes, int n_in,
                              void* d_out, int out_size, void* d_ws, size_t ws_size,
                              hipStream_t stream) {
    const float* x     = (const float*)d_in[0];
    const float* theta = (const float*)d_in[1];
    float* out = (float*)d_out;

    dim3 block(64, NG, 1);
    int nblocks = NB * (HH / 2) * 2;   // 1024
    qconv_kernel<<<nblocks, block, 0, stream>>>(x, theta, out);
}

// Round 8
// 85.524 us; speedup vs baseline: 2.1907x; 2.1907x over previous
//
#include <hip/hip_runtime.h>

#define OC 32
#define IC 16
#define HH 128
#define WW 128
#define NB 8
#define NG 4              // channel groups (threadIdx.y)
#define CPG (OC / NG)     // 8 channels per group
#define NM (IC * 3)       // 48 (j,k) pairs

// Thread = (w-lane, channel group), computes 2 h-pixels x 8 channels.
// Block: threadIdx.x in [0,64) -> w within 64-chunk, threadIdx.y -> group.
// Grid: bid = n*128 + hpair*2 + wchunk   (8*64*2 = 1024 blocks)
// NOTE: unroll on j is capped at 2 — unroll 4 spilled (~1.2KB/thread scratch,
// 328MB HBM writes, 133us). Round-2-style unroll 2 fits under the 128-VGPR
// cap from __launch_bounds__(256,4).
__global__ __launch_bounds__(256, 4) void qconv_kernel(
        const float* __restrict__ x,
        const float* __restrict__ theta,
        float* __restrict__ out) {
    __shared__ float cw_s[NM * OC];
    __shared__ float sw_s[NM * OC];

    int t = threadIdx.y * 64 + threadIdx.x;
#pragma unroll
    for (int q = t; q < NM * OC; q += 256) {
        int m = q >> 5;
        int i = q & 31;
        int j = m / 3;
        int k = m - j * 3;
        float v = theta[(i * j) * 3 + k];
        float sn, cs;
        __sincosf(v, &sn, &cs);
        cw_s[q] = cs;
        sw_s[q] = -sn;
    }
    __syncthreads();

    int bid = blockIdx.x;
    int wbase = (bid & 1) * 64;
    int hp = (bid >> 1) & 63;
    int n = bid >> 7;
    int h0 = hp * 2;
    int w = wbase + threadIdx.x;
    int g = threadIdx.y;

    float acc0[CPG], acc1[CPG];
#pragma unroll
    for (int c = 0; c < CPG; ++c) { acc0[c] = 0.f; acc1[c] = 0.f; }

    const float* xn = x + (size_t)n * IC * HH * WW;
    const float* cwg = cw_s + g * CPG;
    const float* swg = sw_s + g * CPG;

    bool wl = (w > 0), wr = (w < WW - 1);

#pragma unroll 2
    for (int j = 0; j < IC; ++j) {
        const float* xj = xn + j * HH * WW;
        // window sums for rows h0-1 .. h0+2
        float rs[4];
#pragma unroll
        for (int tt = 0; tt < 4; ++tt) {
            int r = h0 - 1 + tt;
            float s = 0.f;
            if (r >= 0 && r < HH) {
                const float* row = xj + r * WW;
                float c0 = row[w];
                float cm = wl ? row[w - 1] : 0.f;
                float cp = wr ? row[w + 1] : 0.f;
                s = cm + c0 + cp;
            }
            rs[tt] = s;
        }
        float sn[4], cs[4];
#pragma unroll
        for (int tt = 0; tt < 4; ++tt) __sincosf(rs[tt], &sn[tt], &cs[tt]);

#pragma unroll
        for (int k = 0; k < 3; ++k) {
            int m = j * 3 + k;
            const float4* c4 = (const float4*)(cwg + m * OC);
            const float4* s4 = (const float4*)(swg + m * OC);
            float cs0 = cs[k], sn0 = sn[k];
            float cs1 = cs[k + 1], sn1 = sn[k + 1];
#pragma unroll
            for (int q = 0; q < 2; ++q) {
                float4 cc = c4[q];
                float4 ss = s4[q];
                acc0[4*q+0] = fmaf(cs0, cc.x, fmaf(sn0, ss.x, acc0[4*q+0]));
                acc0[4*q+1] = fmaf(cs0, cc.y, fmaf(sn0, ss.y, acc0[4*q+1]));
                acc0[4*q+2] = fmaf(cs0, cc.z, fmaf(sn0, ss.z, acc0[4*q+2]));
                acc0[4*q+3] = fmaf(cs0, cc.w, fmaf(sn0, ss.w, acc0[4*q+3]));
                acc1[4*q+0] = fmaf(cs1, cc.x, fmaf(sn1, ss.x, acc1[4*q+0]));
                acc1[4*q+1] = fmaf(cs1, cc.y, fmaf(sn1, ss.y, acc1[4*q+1]));
                acc1[4*q+2] = fmaf(cs1, cc.z, fmaf(sn1, ss.z, acc1[4*q+2]));
                acc1[4*q+3] = fmaf(cs1, cc.w, fmaf(sn1, ss.w, acc1[4*q+3]));
            }
        }
    }

    const float inv3 = 1.0f / 3.0f;
    float* outp = out + ((size_t)n * OC + g * CPG) * HH * WW + (size_t)h0 * WW + w;
#pragma unroll
    for (int c = 0; c < CPG; ++c) {
        outp[(size_t)c * HH * WW]      = acc0[c] * inv3;
        outp[(size_t)c * HH * WW + WW] = acc1[c] * inv3;
    }
}

extern "C" void kernel_launch(void* const* d_in, const int* in_sizes, int n_in,
                              void* d_out, int out_size, void* d_ws, size_t ws_size,
                              hipStream_t stream) {
    const float* x     = (const float*)d_in[0];
    const float* theta = (const float*)d_in[1];
    float* out = (float*)d_out;

    dim3 block(64, NG, 1);
    int nblocks = NB * (HH / 2) * 2;   // 1024
    qconv_kernel<<<nblocks, block, 0, stream>>>(x, theta, out);
}

// Round 9
// 82.896 us; speedup vs baseline: 2.2601x; 1.0317x over previous
//
#include <hip/hip_runtime.h>

#define OC 32
#define IC 16
#define HH 128
#define WW 128
#define NB 8
#define NG 4              // channel groups (threadIdx.y)
#define CPG (OC / NG)     // 8 channels per group
#define NM (IC * 3)       // 48 (j,k) pairs
#define JH 8              // j-half size

// Block covers (n, hpair, wchunk): 2 output rows x 64 w x all 32 channels.
// Phase A (per j-half): threads cooperatively compute sincos(window row sums)
//   ONCE into LDS (row = tid.y in [0,4) -> h0-1..h0+2, 8 j's, 64 w's).
// Phase B: thread (w, group) does the 96-FMA/j channel reduction for
//   2 pixels x 8 channels, reading trig from LDS (stride-8B, conflict-free)
//   and weights as wave-broadcast float2.
// Grid: bid = n*128 + hpair*2 + wchunk = 1024 blocks = exactly 4/CU.
__global__ __launch_bounds__(256, 4) void qconv_kernel(
        const float* __restrict__ x,
        const float* __restrict__ theta,
        float* __restrict__ out) {
    __shared__ float2 wgt_s[NM * OC];        // (cos th, -sin th): 12 KB
    __shared__ float2 trig_s[4][JH][64];     // (cos R, sin R):    16 KB

    int tx = threadIdx.x;        // w lane
    int ty = threadIdx.y;        // row in phase A, channel group in phase B
    int t = ty * 64 + tx;

    int bid = blockIdx.x;
    int wbase = (bid & 1) * 64;
    int hp = (bid >> 1) & 63;
    int n = bid >> 7;
    int h0 = hp * 2;
    int w = wbase + tx;

    // ---- weight fill (once) ----
#pragma unroll
    for (int q = t; q < NM * OC; q += 256) {
        int m = q >> 5;
        int i = q & 31;
        int j = m / 3;
        int k = m - j * 3;
        float v = theta[(i * j) * 3 + k];
        float sn, cs;
        __sincosf(v, &sn, &cs);
        wgt_s[q] = make_float2(cs, -sn);
    }

    const float* xn = x + (size_t)n * IC * HH * WW;
    int r = h0 - 1 + ty;
    bool valid = (r >= 0) && (r < HH);
    bool wl = (w > 0), wr = (w < WW - 1);

    float acc0[CPG], acc1[CPG];
#pragma unroll
    for (int c = 0; c < CPG; ++c) { acc0[c] = 0.f; acc1[c] = 0.f; }

    for (int half = 0; half < 2; ++half) {
        if (half) __syncthreads();   // protect previous half's trig reads
        // ---- Phase A: trig fill for j in [half*8, half*8+8) ----
#pragma unroll 4
        for (int jj = 0; jj < JH; ++jj) {
            int j = half * JH + jj;
            float s = 0.f;
            if (valid) {
                const float* row = xn + ((size_t)j * HH + r) * WW;
                float c0 = row[w];
                float cm = wl ? row[w - 1] : 0.f;
                float cp = wr ? row[w + 1] : 0.f;
                s = cm + c0 + cp;
            }
            float sn, cs;
            __sincosf(s, &sn, &cs);
            trig_s[ty][jj][tx] = make_float2(cs, sn);
        }
        __syncthreads();

        // ---- Phase B: channel reduction ----
#pragma unroll 2
        for (int jj = 0; jj < JH; ++jj) {
            int j = half * JH + jj;
            float2 v0 = trig_s[0][jj][tx];
            float2 v1 = trig_s[1][jj][tx];
            float2 v2 = trig_s[2][jj][tx];
            float2 v3 = trig_s[3][jj][tx];
            float csA[4] = {v0.x, v1.x, v2.x, v3.x};
            float snA[4] = {v0.y, v1.y, v2.y, v3.y};
#pragma unroll
            for (int k = 0; k < 3; ++k) {
                const float2* wm = wgt_s + (j * 3 + k) * OC + ty * CPG;
                float cs0 = csA[k],     sn0 = snA[k];
                float cs1 = csA[k + 1], sn1 = snA[k + 1];
#pragma unroll
                for (int c = 0; c < CPG; ++c) {
                    float2 wv = wm[c];   // broadcast (uniform addr per wave)
                    acc0[c] = fmaf(cs0, wv.x, fmaf(sn0, wv.y, acc0[c]));
                    acc1[c] = fmaf(cs1, wv.x, fmaf(sn1, wv.y, acc1[c]));
                }
            }
        }
    }

    const float inv3 = 1.0f / 3.0f;
    float* outp = out + ((size_t)n * OC + ty * CPG) * HH * WW + (size_t)h0 * WW + w;
#pragma unroll
    for (int c = 0; c < CPG; ++c) {
        outp[(size_t)c * HH * WW]      = acc0[c] * inv3;
        outp[(size_t)c * HH * WW + WW] = acc1[c] * inv3;
    }
}

extern "C" void kernel_launch(void* const* d_in, const int* in_sizes, int n_in,
                              void* d_out, int out_size, void* d_ws, size_t ws_size,
                              hipStream_t stream) {
    const float* x     = (const float*)d_in[0];
    const float* theta = (const float*)d_in[1];
    float* out = (float*)d_out;

    dim3 block(64, NG, 1);
    int nblocks = NB * (HH / 2) * 2;   // 1024
    qconv_kernel<<<nblocks, block, 0, stream>>>(x, theta, out);
}

// Round 10
// 74.288 us; speedup vs baseline: 2.5220x; 1.1159x over previous
//
#include <hip/hip_runtime.h>

#define OC 32
#define IC 16
#define HH 128
#define WW 128
#define NB 8
#define STRIDE_DW 52   // LDS row stride in dwords (208B: 16B-aligned, low-conflict)

typedef __attribute__((ext_vector_type(8))) __bf16 bf16x8;
typedef __attribute__((ext_vector_type(4))) float f32x4;

__device__ inline unsigned int f2bf_rne(float f) {
    union { float f; unsigned int u; } v; v.f = f;
    return (v.u + 0x7FFFu + ((v.u >> 16) & 1u)) >> 16;
}
__device__ inline unsigned int pack2bf(float lo, float hi) {
    return f2bf_rne(lo) | (f2bf_rne(hi) << 16);
}

// D[oc][px] = A(32x96) x B(96x128), K = 2*(3j+kk) interleaving (cos,sin):
//   A[oc][2m]=cos(th), A[oc][2m+1]=-sin(th); B[px][2m]=cos(R), B[px][2m+1]=sin(R)
//   => sum_k A*B = sum_m cos(R+th).  px = hrow*64 + w_local (2 rows x 64 w).
// Block (64,4): Phase A builds B_lds cooperatively (rowsum+sincos once),
// then each wave (ty) owns a 32-px slice: 12 MFMA (2 Mt x 2 Nt x 3 Kt).
// Grid 1024 blocks = exactly 4/CU at 33KB LDS.
__global__ __launch_bounds__(256, 4) void qconv_kernel(
        const float* __restrict__ x,
        const float* __restrict__ theta,
        float* __restrict__ out) {
    __shared__ unsigned int A_lds[OC * STRIDE_DW];     // 6.5 KB  weights
    __shared__ unsigned int B_lds[128 * STRIDE_DW];    // 26 KB   trig

    const int tx = threadIdx.x;
    const int ty = threadIdx.y;
    const int t  = ty * 64 + tx;

    const int bid = blockIdx.x;
    const int wbase = (bid & 1) * 64;
    const int hp = (bid >> 1) & 63;
    const int n  = bid >> 7;
    const int h0 = hp * 2;
    const int w  = wbase + tx;

    // ---- weight prep: 6 entries/thread ----
#pragma unroll
    for (int q = t; q < OC * 48; q += 256) {
        int m  = q >> 5;          // 0..47 = 3j+kk
        int oc = q & 31;
        int j  = m / 3;
        int kk = m - 3 * j;
        float th = theta[(oc * j) * 3 + kk];
        float sn, cs;
        __sincosf(th, &sn, &cs);
        A_lds[oc * STRIDE_DW + m] = pack2bf(cs, -sn);
    }

    // ---- Phase A: sincos of row-window sums, written once ----
    const float* xn = x + (size_t)n * IC * HH * WW;
    const int r = h0 - 1 + ty;                 // ty = source row 0..3
    const bool valid = (r >= 0) && (r < HH);
    const bool wlok = (w > 0), wrok = (w < WW - 1);

#pragma unroll 4
    for (int j = 0; j < IC; ++j) {
        float s = 0.f;
        if (valid) {
            const float* row = xn + ((size_t)j * HH + r) * WW;
            float c0 = row[w];
            float cm = wlok ? row[w - 1] : 0.f;
            float cp = wrok ? row[w + 1] : 0.f;
            s = cm + c0 + cp;
        }
        float sn, cs;
        __sincosf(s, &sn, &cs);
        unsigned int pk = pack2bf(cs, sn);
        // source row r = h0-1+ty feeds output row hrow at kk = ty - hrow
        if (ty < 3)  B_lds[(tx)      * STRIDE_DW + 3 * j + ty]     = pk; // hrow 0
        if (ty >= 1) B_lds[(64 + tx) * STRIDE_DW + 3 * j + ty - 1] = pk; // hrow 1
    }
    __syncthreads();

    // ---- MFMA phase: wave ty owns px in [32*ty, 32*ty+32) ----
    const int l15 = tx & 15;
    const int lk  = tx >> 4;
    const char* Ab = (const char*)A_lds;
    const char* Bb = (const char*)B_lds;

    f32x4 acc[2][2];
#pragma unroll
    for (int a = 0; a < 2; ++a)
#pragma unroll
        for (int b = 0; b < 2; ++b) acc[a][b] = (f32x4){0.f, 0.f, 0.f, 0.f};

#pragma unroll
    for (int Kt = 0; Kt < 3; ++Kt) {
        bf16x8 afr[2], bfr[2];
#pragma unroll
        for (int Mt = 0; Mt < 2; ++Mt)
            afr[Mt] = *(const bf16x8*)(Ab + (l15 + 16 * Mt) * 208 + Kt * 64 + lk * 16);
#pragma unroll
        for (int Nt = 0; Nt < 2; ++Nt)
            bfr[Nt] = *(const bf16x8*)(Bb + (ty * 32 + 16 * Nt + l15) * 208 + Kt * 64 + lk * 16);
#pragma unroll
        for (int Mt = 0; Mt < 2; ++Mt)
#pragma unroll
            for (int Nt = 0; Nt < 2; ++Nt)
                acc[Mt][Nt] = __builtin_amdgcn_mfma_f32_16x16x32_bf16(
                    afr[Mt], bfr[Nt], acc[Mt][Nt], 0, 0, 0);
    }

    // ---- epilogue: C col = lane&15 -> px, row = (lane>>4)*4+e -> oc ----
    const float inv3 = 1.0f / 3.0f;
#pragma unroll
    for (int Mt = 0; Mt < 2; ++Mt)
#pragma unroll
        for (int Nt = 0; Nt < 2; ++Nt)
#pragma unroll
            for (int e = 0; e < 4; ++e) {
                int oc = 16 * Mt + lk * 4 + e;
                int px = ty * 32 + 16 * Nt + l15;
                int hrow = px >> 6, wloc = px & 63;
                out[(((size_t)n * OC + oc) * HH + (h0 + hrow)) * WW + (wbase + wloc)]
                    = acc[Mt][Nt][e] * inv3;
            }
}

extern "C" void kernel_launch(void* const* d_in, const int* in_sizes, int n_in,
                              void* d_out, int out_size, void* d_ws, size_t ws_size,
                              hipStream_t stream) {
    const float* x     = (const float*)d_in[0];
    const float* theta = (const float*)d_in[1];
    float* out = (float*)d_out;

    dim3 block(64, 4, 1);
    int nblocks = NB * (HH / 2) * 2;   // 1024
    qconv_kernel<<<nblocks, block, 0, stream>>>(x, theta, out);
}

// Round 13
// 73.652 us; speedup vs baseline: 2.5438x; 1.0086x over previous
//
#include <hip/hip_runtime.h>

#define OC 32
#define IC 16
#define HH 128
#define WW 128
#define NB 8
#define STRIDE_DW 52   // B row stride in dwords (208B: 16B-aligned, 2-way banks = free)

typedef __attribute__((ext_vector_type(8))) __bf16 bf16x8;
typedef __attribute__((ext_vector_type(4))) float f32x4;

#define INV_2PI 0.15915494309189535f

// Pack two floats to bf16x2 via compiler casts (RNE; may fuse to v_cvt_pk_bf16_f32).
__device__ inline unsigned int pack2bf(float lo, float hi) {
    union { __bf16 h[2]; unsigned int u; } p;
    p.h[0] = (__bf16)lo;
    p.h[1] = (__bf16)hi;
    return p.u;
}

// HW sincos: v_sin/v_cos take REVOLUTIONS and do NOT range-reduce (ISA doc:
// "reduce with v_fract_f32 first"). Period in rev-units is exactly 1, so
// fract() is an EXACT reduction. Round-12 failure (absmax 4.0) was missing this.
__device__ inline void hw_sincos(float rad, float* sn, float* cs) {
    float rev = rad * INV_2PI;
    float fr = rev - floorf(rev);   // [0,1)
    *sn = __builtin_amdgcn_sinf(fr);
    *cs = __builtin_amdgcn_cosf(fr);
}

// D[oc][px] = A(32x96) x B(96x128), K = 2*(3j+kk) interleaved (cos,sin):
//   A[oc][2m]=cos(th)/3, A[oc][2m+1]=-sin(th)/3; B[px][2m]=cos(R), B[px][2m+1]=sin(R)
//   => D = (1/3) sum_m cos(R+th).  px = hrow*64 + w_local (2 rows x 64 w).
// Grid 1024 blocks = exactly 4/CU at ~33KB LDS.  (Structure verified round 10.)
__global__ __launch_bounds__(256, 4) void qconv_kernel(
        const float* __restrict__ x,
        const float* __restrict__ theta,
        float* __restrict__ out) {
    __shared__ unsigned int A_lds[OC * STRIDE_DW];     // 6.5 KB  weights (pre-scaled by 1/3)
    __shared__ unsigned int B_lds[128 * STRIDE_DW];    // 26 KB   trig

    const int tx = threadIdx.x;
    const int ty = threadIdx.y;
    const int t  = ty * 64 + tx;

    const int bid = blockIdx.x;
    const int wbase = (bid & 1) * 64;
    const int hp = (bid >> 1) & 63;
    const int n  = bid >> 7;
    const int h0 = hp * 2;
    const int w  = wbase + tx;

    // ---- weight prep: 6 entries/thread ----
    const float inv3 = 1.0f / 3.0f;
#pragma unroll
    for (int q = t; q < OC * 48; q += 256) {
        int m  = q >> 5;          // 0..47 = 3j+kk
        int oc = q & 31;
        int j  = m / 3;
        int kk = m - 3 * j;
        float th = theta[(oc * j) * 3 + kk];
        float sn, cs;
        hw_sincos(th, &sn, &cs);
        A_lds[oc * STRIDE_DW + m] = pack2bf(cs * inv3, -sn * inv3);
    }

    // ---- Phase A: sincos of row-window sums, written once ----
    const float* xn = x + (size_t)n * IC * HH * WW;
    const int r = h0 - 1 + ty;                 // ty = source row 0..3
    const bool valid = (r >= 0) && (r < HH);
    const bool wlok = (w > 0), wrok = (w < WW - 1);

#pragma unroll
    for (int j = 0; j < IC; ++j) {
        float s = 0.f;
        if (valid) {
            const float* row = xn + ((size_t)j * HH + r) * WW;
            float c0 = row[w];
            float cm = wlok ? row[w - 1] : 0.f;
            float cp = wrok ? row[w + 1] : 0.f;
            s = cm + c0 + cp;
        }
        float sn, cs;
        hw_sincos(s, &sn, &cs);
        unsigned int pk = pack2bf(cs, sn);
        // source row r = h0-1+ty feeds output row hrow at kk = ty - hrow
        if (ty < 3)  B_lds[(tx)      * STRIDE_DW + 3 * j + ty]     = pk; // hrow 0
        if (ty >= 1) B_lds[(64 + tx) * STRIDE_DW + 3 * j + ty - 1] = pk; // hrow 1
    }
    __syncthreads();

    // ---- MFMA phase: wave ty owns px in [32*ty, 32*ty+32) ----
    const int l15 = tx & 15;
    const int lk  = tx >> 4;
    const char* Ab = (const char*)A_lds;
    const char* Bb = (const char*)B_lds;

    f32x4 acc[2][2];
#pragma unroll
    for (int a = 0; a < 2; ++a)
#pragma unroll
        for (int b = 0; b < 2; ++b) acc[a][b] = (f32x4){0.f, 0.f, 0.f, 0.f};

#pragma unroll
    for (int Kt = 0; Kt < 3; ++Kt) {
        bf16x8 afr[2], bfr[2];
#pragma unroll
        for (int Mt = 0; Mt < 2; ++Mt)
            afr[Mt] = *(const bf16x8*)(Ab + (l15 + 16 * Mt) * 208 + Kt * 64 + lk * 16);
#pragma unroll
        for (int Nt = 0; Nt < 2; ++Nt)
            bfr[Nt] = *(const bf16x8*)(Bb + (ty * 32 + 16 * Nt + l15) * 208 + Kt * 64 + lk * 16);
#pragma unroll
        for (int Mt = 0; Mt < 2; ++Mt)
#pragma unroll
            for (int Nt = 0; Nt < 2; ++Nt)
                acc[Mt][Nt] = __builtin_amdgcn_mfma_f32_16x16x32_bf16(
                    afr[Mt], bfr[Nt], acc[Mt][Nt], 0, 0, 0);
    }

    // ---- epilogue: C col = lane&15 -> px, row = (lane>>4)*4+e -> oc ----
    // (1/3 already folded into A)
#pragma unroll
    for (int Mt = 0; Mt < 2; ++Mt)
#pragma unroll
        for (int Nt = 0; Nt < 2; ++Nt)
#pragma unroll
            for (int e = 0; e < 4; ++e) {
                int oc = 16 * Mt + lk * 4 + e;
                int px = ty * 32 + 16 * Nt + l15;
                int hrow = px >> 6, wloc = px & 63;
                out[(((size_t)n * OC + oc) * HH + (h0 + hrow)) * WW + (wbase + wloc)]
                    = acc[Mt][Nt][e];
            }
}

extern "C" void kernel_launch(void* const* d_in, const int* in_sizes, int n_in,
                              void* d_out, int out_size, void* d_ws, size_t ws_size,
                              hipStream_t stream) {
    const float* x     = (const float*)d_in[0];
    const float* theta = (const float*)d_in[1];
    float* out = (float*)d_out;

    dim3 block(64, 4, 1);
    int nblocks = NB * (HH / 2) * 2;   // 1024
    qconv_kernel<<<nblocks, block, 0, stream>>>(x, theta, out);
}